// Round 7
// baseline (223.180 us; speedup 1.0000x reference)
//
#include <hip/hip_runtime.h>
#include <math.h>

#define EMBED   256
#define M_HEADS 8
#define DVAL    32
#define LK      16
#define S_TOTAL 21760
#define NQ      8192
#define NROWS   (2 * NQ)          // 16384 total query rows
#define QBS     16                // queries per block (sample)

typedef __attribute__((ext_vector_type(8))) short s16x8;
typedef __attribute__((ext_vector_type(4))) float f32x4;
typedef unsigned short u16;
typedef unsigned int   u32;

__device__ __forceinline__ short f2bf(float f) {
    unsigned u = __float_as_uint(f);
    u += 0x7fffu + ((u >> 16) & 1u);
    return (short)(u >> 16);
}
__device__ __forceinline__ float bf2f(short h) {
    return __uint_as_float(((unsigned)(u16)h) << 16);
}

// ---------------- workspace layout (float offsets) ----------------
#define V_OFF     0                      // value table, bf16: 11,141,120 shorts
#define V_FLTS    5570560
#define PA_OFF    (V_OFF + V_FLTS)       // (x,y,attn) fp32 triples
#define PA_FLTS   6291456
#define QHI_OFF   (PA_OFF + PA_FLTS)     // query hi-plane bf16 [16384][256]
#define QPL_FLTS  2097152
#define QLO_OFF   (QHI_OFF + QPL_FLTS)   // query lo-plane
#define MID_OFF   (QLO_OFF + QPL_FLTS)   // mid bf16 [16384][256]
#define MID_FLTS  2097152
#define WHI_OFF   (MID_OFF + MID_FLTS)   // packed [W_off|W_attn] hi, C=384
#define WOA_FLTS  49152
#define WLO_OFF   (WHI_OFF + WOA_FLTS)
#define WV_OFF    (WLO_OFF + WOA_FLTS)   // packed W_val bf16, C=256
#define WO_OFF    (WV_OFF + 32768)       // packed W_out bf16, C=256

// ---------------------------------------------------------------------------
// prep_kernel: fused presplit (blocks 0..4095) + W_val pack (4096..4351) +
// W_out pack (4352..4607) + [W_off|W_attn] hi/lo pack (4608..4991).
// ---------------------------------------------------------------------------
__global__ __launch_bounds__(256) void prep_kernel(
    const float* __restrict__ q,     u16* __restrict__ qh, u16* __restrict__ ql,
    const float* __restrict__ W_off, const float* __restrict__ W_attn,
    u16* __restrict__ Whi,           u16* __restrict__ Wlo,
    const float* __restrict__ W_val, u16* __restrict__ Wv,
    const float* __restrict__ W_out, u16* __restrict__ Wo)
{
    const int b = blockIdx.x;
    const int t = threadIdx.x;

    if (b < 4096) {                       // presplit queries -> hi/lo bf16
        const int i4 = b * 256 + t;
        const float4 v = ((const float4*)q)[i4];
        short4 h, l;
        h.x = f2bf(v.x); l.x = f2bf(v.x - bf2f(h.x));
        h.y = f2bf(v.y); l.y = f2bf(v.y - bf2f(h.y));
        h.z = f2bf(v.z); l.z = f2bf(v.z - bf2f(h.z));
        h.w = f2bf(v.w); l.w = f2bf(v.w - bf2f(h.w));
        ((short4*)qh)[i4] = h;
        ((short4*)ql)[i4] = l;
    } else if (b < 4096 + 512) {          // pack W_val / W_out (C=256)
        const int flat = (b - 4096) * 256 + t;       // 0..131071
        const int which = flat >> 16;                // 0: W_val, 1: W_out
        const int e = flat & 65535;
        const int k = e >> 8, c = e & 255;
        const float f = which ? W_out[k * 256 + c] : W_val[k * 256 + c];
        const int kt = k >> 5, qd = (k >> 3) & 3, j = k & 7;
        const int idx = (((kt * 256 + c) << 2) + qd) * 8 + j;
        (which ? Wo : Wv)[idx] = (u16)f2bf(f);
    } else {                              // pack [W_off|W_attn] hi/lo (C=384)
        const int flat = (b - 4608) * 256 + t;       // 0..98303
        const int k = flat / 384, c = flat - k * 384;
        const float f = (c < 256) ? W_off[k * 256 + c] : W_attn[k * 128 + (c - 256)];
        const short h = f2bf(f);
        const short lo = f2bf(f - bf2f(h));
        const int kt = k >> 5, qd = (k >> 3) & 3, j = k & 7;
        const int idx = (((kt * 384 + c) << 2) + qd) * 8 + j;
        Whi[idx] = (u16)h;
        Wlo[idx] = (u16)lo;
    }
}

// ---------------------------------------------------------------------------
// Kernel 1 (MFMA, read-once): v = mask * (value @ W_val + b_val), per-head
// bf16 layout v_out[((n*M + m)*S_TOTAL + s)*32 + d].
// Each wave: 16 rows x FULL 256 cols (16 n-tiles) -> one A-frag feeds 16
// MFMAs, value is fetched exactly once. 64 rows/block, grid 680.
// ---------------------------------------------------------------------------
__global__ __launch_bounds__(256) void vproj_kernel(
    const float* __restrict__ value,
    const float* __restrict__ vmask,
    const u16* __restrict__ Wpk,
    const float* __restrict__ b_val,
    u16* __restrict__ v_out)
{
    const int t  = threadIdx.x;
    const int w  = t >> 6, l = t & 63;
    const int c  = l & 15, qd = l >> 4;
    const int r0 = blockIdx.x * 64 + w * 16;

    f32x4 acc[16] = {};

    for (int kt = 0; kt < 8; ++kt) {
        const float* ap = value + (size_t)(r0 + c) * EMBED + kt * 32 + qd * 8;
        const float4 a0 = *(const float4*)ap;
        const float4 a1 = *(const float4*)(ap + 4);
        const s16x8 a = (s16x8){ f2bf(a0.x), f2bf(a0.y), f2bf(a0.z), f2bf(a0.w),
                                 f2bf(a1.x), f2bf(a1.y), f2bf(a1.z), f2bf(a1.w) };
        s16x8 b[16];
        #pragma unroll
        for (int nt = 0; nt < 16; ++nt)
            b[nt] = *(const s16x8*)(Wpk + (((kt * 256 + nt * 16 + c) << 2) + qd) * 8);
        #pragma unroll
        for (int nt = 0; nt < 16; ++nt)
            acc[nt] = __builtin_amdgcn_mfma_f32_16x16x32_bf16(a, b[nt], acc[nt], 0, 0, 0);
    }

    #pragma unroll
    for (int r = 0; r < 4; ++r) {
        const int grow = r0 + qd * 4 + r;
        const int n = (grow >= S_TOTAL) ? 1 : 0;
        const int s = grow - n * S_TOTAL;
        const float mk = vmask[grow];
        #pragma unroll
        for (int nt = 0; nt < 16; ++nt) {
            const int col = nt * 16 + c;
            const int hm = col >> 5, d = col & 31;
            v_out[((size_t)(n * M_HEADS + hm) * S_TOTAL + s) * DVAL + d] =
                (u16)f2bf((acc[nt][r] + b_val[col]) * mk);
        }
    }
}

// ---------------------------------------------------------------------------
// Kernel 2 (split-bf16 MFMA): [offsets | attn] = q @ [W_off|W_attn] + bias
// via 3-pass hi/lo MFMA. 32 query rows per block, 384 cols, 4 waves x 96.
// Epilogue: softmax + position math -> pa triples.
// ---------------------------------------------------------------------------
__global__ __launch_bounds__(256) void qproj_kernel(
    const u16* __restrict__ q_hi, const u16* __restrict__ q_lo,
    const float* __restrict__ qgl,
    const u16* __restrict__ Whi, const u16* __restrict__ Wlo,
    const float* __restrict__ b_off, const float* __restrict__ b_attn,
    float* __restrict__ pa)
{
    __shared__ float s_off[32][260];
    __shared__ float s_attn[32][132];
    __shared__ float s_geom[32][4];

    const int t  = threadIdx.x;
    const int w  = t >> 6, l = t & 63;
    const int c  = l & 15, qd = l >> 4;
    const int row0 = blockIdx.x * 32;
    const int c0 = w * 96;

    if (t < 32) {
        const float* g = &qgl[(size_t)(row0 + t) * 4];
        s_geom[t][0] = 1.f / (1.f + __expf(-g[0]));
        s_geom[t][1] = 1.f / (1.f + __expf(-g[1]));
        s_geom[t][2] = (1.f / (1.f + __expf(-g[2]))) * 0.125f;
        s_geom[t][3] = (1.f / (1.f + __expf(-g[3]))) * 0.125f;
    }

    f32x4 acc[2][6] = {};

    for (int kt = 0; kt < 8; ++kt) {
        s16x8 ah[2], al[2], bh[6], bl[6];
        #pragma unroll
        for (int mt = 0; mt < 2; ++mt) {
            const size_t ao = (size_t)(row0 + mt * 16 + c) * EMBED + kt * 32 + qd * 8;
            ah[mt] = *(const s16x8*)(q_hi + ao);
            al[mt] = *(const s16x8*)(q_lo + ao);
        }
        #pragma unroll
        for (int nt = 0; nt < 6; ++nt) {
            const int idx = (((kt * 384 + c0 + nt * 16 + c) << 2) + qd) * 8;
            bh[nt] = *(const s16x8*)(Whi + idx);
            bl[nt] = *(const s16x8*)(Wlo + idx);
        }
        #pragma unroll
        for (int mt = 0; mt < 2; ++mt)
            #pragma unroll
            for (int nt = 0; nt < 6; ++nt) {
                acc[mt][nt] = __builtin_amdgcn_mfma_f32_16x16x32_bf16(ah[mt], bh[nt], acc[mt][nt], 0, 0, 0);
                acc[mt][nt] = __builtin_amdgcn_mfma_f32_16x16x32_bf16(ah[mt], bl[nt], acc[mt][nt], 0, 0, 0);
                acc[mt][nt] = __builtin_amdgcn_mfma_f32_16x16x32_bf16(al[mt], bh[nt], acc[mt][nt], 0, 0, 0);
            }
    }

    #pragma unroll
    for (int mt = 0; mt < 2; ++mt)
        #pragma unroll
        for (int nt = 0; nt < 6; ++nt) {
            const int col = c0 + nt * 16 + c;
            #pragma unroll
            for (int r = 0; r < 4; ++r) {
                const int row = mt * 16 + qd * 4 + r;
                if (col < 256) s_off[row][col] = acc[mt][nt][r] + b_off[col];
                else           s_attn[row][col - 256] = acc[mt][nt][r] + b_attn[col - 256];
            }
        }
    __syncthreads();

    {
        const int qi = t >> 3, hm = t & 7;
        float* a = &s_attn[qi][hm * LK];
        float mx = a[0];
        #pragma unroll
        for (int i = 1; i < LK; ++i) mx = fmaxf(mx, a[i]);
        float s = 0.f;
        #pragma unroll
        for (int i = 0; i < LK; ++i) { const float e = __expf(a[i] - mx); a[i] = e; s += e; }
        const float inv = 1.f / s;
        #pragma unroll
        for (int i = 0; i < LK; ++i) a[i] *= inv;
    }
    __syncthreads();

    for (int p = t; p < 32 * 128; p += 256) {
        const int qi = p >> 7;
        const int pt = p & 127;
        const int lvl = (pt & 15) >> 2;
        const float Wl = (float)(128 >> lvl);
        const float px = fmaf(s_off[qi][2 * pt + 0], s_geom[qi][2], s_geom[qi][0]);
        const float py = fmaf(s_off[qi][2 * pt + 1], s_geom[qi][3], s_geom[qi][1]);
        const float gx = fminf(fmaxf(2.f * px - 1.f, -1.f), 1.f);
        const float gy = fminf(fmaxf(2.f * py - 1.f, -1.f), 1.f);
        const float x = (gx + 1.f) * (Wl * 0.5f) - 0.5f;
        const float y = (gy + 1.f) * (Wl * 0.5f) - 0.5f;
        const size_t idx = ((size_t)(row0 + qi) * 128 + pt) * 3;
        pa[idx + 0] = x;
        pa[idx + 1] = y;
        pa[idx + 2] = s_attn[qi][pt];
    }
}

// ---------------------------------------------------------------------------
// Kernel 3: bilinear sampling. Setup: 256 pts/block -> LDS int4 offsets +
// float4 weights. Main: 2 bf16 channels per lane via dword gathers.
// m = blk&7 keeps one head's slice L2-local per XCD.
// ---------------------------------------------------------------------------
__global__ __launch_bounds__(256) void sample_kernel(
    const float* __restrict__ pa,
    const u16* __restrict__ v_tab,
    u16* __restrict__ mid)
{
    __shared__ int4   s_idx[QBS * 17];
    __shared__ float4 s_w[QBS * 17];

    const int t    = threadIdx.x;
    const int m    = blockIdx.x & 7;
    const int rest = blockIdx.x >> 3;
    const int qc   = rest & 511;
    const int n    = rest >> 9;
    const int q0   = qc * QBS;

    {
        const int qi = t >> 4, lk = t & 15;
        const int lvl   = lk >> 2;
        const int Wl    = 128 >> lvl;
        const int start = (lvl == 0) ? 0 : (lvl == 1) ? 16384 : (lvl == 2) ? 20480 : 21504;

        const size_t prow = ((size_t)(n * NQ + q0 + qi)) * 128 + m * 16 + lk;
        const float x  = pa[prow * 3 + 0];
        const float y  = pa[prow * 3 + 1];
        const float aw = pa[prow * 3 + 2];

        const float x0f = floorf(x), y0f = floorf(y);
        const int   x0 = (int)x0f, y0 = (int)y0f;
        const float wx = x - x0f, wy = y - y0f;

        const float vx0 = (x0 >= 0) ? 1.f : 0.f;
        const float vx1 = (x0 + 1 <= Wl - 1) ? 1.f : 0.f;
        const float vy0 = (y0 >= 0) ? 1.f : 0.f;
        const float vy1 = (y0 + 1 <= Wl - 1) ? 1.f : 0.f;

        const int xc0 = max(x0, 0);
        const int xc1 = min(x0 + 1, Wl - 1);
        const int yc0 = max(y0, 0);
        const int yc1 = min(y0 + 1, Wl - 1);

        const int e = qi * 17 + lk;
        s_idx[e] = make_int4((start + yc0 * Wl + xc0) * DVAL,
                             (start + yc0 * Wl + xc1) * DVAL,
                             (start + yc1 * Wl + xc0) * DVAL,
                             (start + yc1 * Wl + xc1) * DVAL);
        s_w[e] = make_float4(aw * (1.f - wx) * (1.f - wy) * vx0 * vy0,
                             aw * wx * (1.f - wy) * vx1 * vy0,
                             aw * (1.f - wx) * wy * vx0 * vy1,
                             aw * wx * wy * vx1 * vy1);
    }
    __syncthreads();

    const int g = t >> 4, dp = t & 15;
    const u16* __restrict__ vbp =
        v_tab + (size_t)(n * M_HEADS + m) * S_TOTAL * DVAL + 2 * dp;

    float acc0 = 0.f, acc1 = 0.f;
    #pragma unroll
    for (int lk = 0; lk < LK; ++lk) {
        const int4   id = s_idx[g * 17 + lk];
        const float4 w  = s_w[g * 17 + lk];
        const u32 u0 = *(const u32*)(vbp + id.x);
        const u32 u1 = *(const u32*)(vbp + id.y);
        const u32 u2 = *(const u32*)(vbp + id.z);
        const u32 u3 = *(const u32*)(vbp + id.w);
        acc0 = fmaf(w.x, __uint_as_float(u0 << 16), acc0);
        acc1 = fmaf(w.x, __uint_as_float(u0 & 0xffff0000u), acc1);
        acc0 = fmaf(w.y, __uint_as_float(u1 << 16), acc0);
        acc1 = fmaf(w.y, __uint_as_float(u1 & 0xffff0000u), acc1);
        acc0 = fmaf(w.z, __uint_as_float(u2 << 16), acc0);
        acc1 = fmaf(w.z, __uint_as_float(u2 & 0xffff0000u), acc1);
        acc0 = fmaf(w.w, __uint_as_float(u3 << 16), acc0);
        acc1 = fmaf(w.w, __uint_as_float(u3 & 0xffff0000u), acc1);
    }

    const u32 packed = ((u32)(u16)f2bf(acc1) << 16) | (u32)(u16)f2bf(acc0);
    *(u32*)(mid + ((size_t)(n * NQ + q0 + g)) * EMBED + m * DVAL + 2 * dp) = packed;
}

// ---------------------------------------------------------------------------
// Kernel 4 (MFMA, LDS-free): out = mid @ W_out + b_out.
// ---------------------------------------------------------------------------
__global__ __launch_bounds__(256) void out_kernel(
    const u16* __restrict__ mid,
    const u16* __restrict__ Wpk,
    const float* __restrict__ b_out,
    float* __restrict__ out)
{
    const int t  = threadIdx.x;
    const int w  = t >> 6, l = t & 63;
    const int c  = l & 15, qd = l >> 4;
    const int r0 = blockIdx.y * 128 + w * 32;
    const int c0 = blockIdx.x * 64;

    f32x4 acc[2][4] = {};

    for (int kt = 0; kt < 8; ++kt) {
        s16x8 a[2], b[4];
        #pragma unroll
        for (int mt = 0; mt < 2; ++mt)
            a[mt] = *(const s16x8*)(mid + (size_t)(r0 + mt * 16 + c) * EMBED + kt * 32 + qd * 8);
        #pragma unroll
        for (int nt = 0; nt < 4; ++nt)
            b[nt] = *(const s16x8*)(Wpk + (((kt * 256 + c0 + nt * 16 + c) << 2) + qd) * 8);
        #pragma unroll
        for (int mt = 0; mt < 2; ++mt)
            #pragma unroll
            for (int nt = 0; nt < 4; ++nt)
                acc[mt][nt] = __builtin_amdgcn_mfma_f32_16x16x32_bf16(a[mt], b[nt], acc[mt][nt], 0, 0, 0);
    }

    #pragma unroll
    for (int mt = 0; mt < 2; ++mt)
        #pragma unroll
        for (int r = 0; r < 4; ++r) {
            const int row = r0 + mt * 16 + qd * 4 + r;
            #pragma unroll
            for (int nt = 0; nt < 4; ++nt) {
                const int col = c0 + nt * 16 + c;
                out[(size_t)row * EMBED + col] = acc[mt][nt][r] + b_out[col];
            }
        }
}

// ---------------------------------------------------------------------------
extern "C" void kernel_launch(void* const* d_in, const int* in_sizes, int n_in,
                              void* d_out, int out_size, void* d_ws, size_t ws_size,
                              hipStream_t stream) {
    (void)in_sizes; (void)n_in; (void)out_size; (void)ws_size;

    const float* queries = (const float*)d_in[0];
    const float* qgl     = (const float*)d_in[1];
    const float* value   = (const float*)d_in[2];
    const float* vmask   = (const float*)d_in[3];
    const float* W_off   = (const float*)d_in[4];
    const float* b_off   = (const float*)d_in[5];
    const float* W_attn  = (const float*)d_in[6];
    const float* b_attn  = (const float*)d_in[7];
    const float* W_val   = (const float*)d_in[8];
    const float* b_val   = (const float*)d_in[9];
    const float* W_out   = (const float*)d_in[10];
    const float* b_out   = (const float*)d_in[11];

    float* ws   = (float*)d_ws;
    u16*  v_ws  = (u16*)(ws + V_OFF);
    float* pa   = ws + PA_OFF;
    u16*  q_hi  = (u16*)(ws + QHI_OFF);
    u16*  q_lo  = (u16*)(ws + QLO_OFF);
    u16*  mid   = (u16*)(ws + MID_OFF);
    u16*  whi   = (u16*)(ws + WHI_OFF);
    u16*  wlo   = (u16*)(ws + WLO_OFF);
    u16*  wvpk  = (u16*)(ws + WV_OFF);
    u16*  wopk  = (u16*)(ws + WO_OFF);
    float* outp = (float*)d_out;

    prep_kernel<<<4992, 256, 0, stream>>>(queries, q_hi, q_lo,
                                          W_off, W_attn, whi, wlo,
                                          W_val, wvpk, W_out, wopk);

    vproj_kernel<<<680, 256, 0, stream>>>(value, vmask, wvpk, b_val, v_ws);
    qproj_kernel<<<NROWS / 32, 256, 0, stream>>>(q_hi, q_lo, qgl, whi, wlo,
                                                 b_off, b_attn, pa);
    sample_kernel<<<2 * (NQ / QBS) * M_HEADS, 256, 0, stream>>>(pa, v_ws, mid);
    out_kernel<<<dim3(4, 128), 256, 0, stream>>>(mid, wopk, b_out, outp);
}

// Round 8
// 213.683 us; speedup vs baseline: 1.0444x; 1.0444x over previous
//
#include <hip/hip_runtime.h>
#include <math.h>

#define EMBED   256
#define M_HEADS 8
#define DVAL    32
#define LK      16
#define S_TOTAL 21760
#define NQ      8192
#define NROWS   (2 * NQ)          // 16384 total query rows
#define QBS     16                // queries per block (sample)

typedef __attribute__((ext_vector_type(8))) short s16x8;
typedef __attribute__((ext_vector_type(4))) float f32x4;
typedef unsigned short u16;
typedef unsigned int   u32;

__device__ __forceinline__ short f2bf(float f) {
    unsigned u = __float_as_uint(f);
    u += 0x7fffu + ((u >> 16) & 1u);
    return (short)(u >> 16);
}
__device__ __forceinline__ float bf2f(short h) {
    return __uint_as_float(((unsigned)(u16)h) << 16);
}

// ---------------- workspace layout (float offsets) ----------------
#define V_OFF     0                      // value table, bf16: 11,141,120 shorts
#define V_FLTS    5570560
#define PA_OFF    (V_OFF + V_FLTS)       // (x,y,attn) fp32 triples
#define PA_FLTS   6291456
#define MID_OFF   (PA_OFF + PA_FLTS)     // mid bf16 [16384][256]
#define MID_FLTS  2097152
#define WHI_OFF   (MID_OFF + MID_FLTS)   // packed [W_off|W_attn] hi, C=384
#define WOA_FLTS  49152
#define WLO_OFF   (WHI_OFF + WOA_FLTS)
#define WV_OFF    (WLO_OFF + WOA_FLTS)   // packed W_val bf16, C=256
#define WO_OFF    (WV_OFF + 32768)       // packed W_out bf16, C=256

// ---------------------------------------------------------------------------
// prep_kernel (weight packs only): blocks 0..511 pack W_val/W_out (C=256),
// blocks 512..895 pack [W_off|W_attn] hi/lo (C=384).
// ---------------------------------------------------------------------------
__global__ __launch_bounds__(256) void prep_kernel(
    const float* __restrict__ W_off, const float* __restrict__ W_attn,
    u16* __restrict__ Whi,           u16* __restrict__ Wlo,
    const float* __restrict__ W_val, u16* __restrict__ Wv,
    const float* __restrict__ W_out, u16* __restrict__ Wo)
{
    const int b = blockIdx.x;
    const int t = threadIdx.x;

    if (b < 512) {                        // pack W_val / W_out (C=256)
        const int flat = b * 256 + t;                // 0..131071
        const int which = flat >> 16;                // 0: W_val, 1: W_out
        const int e = flat & 65535;
        const int k = e >> 8, c = e & 255;
        const float f = which ? W_out[k * 256 + c] : W_val[k * 256 + c];
        const int kt = k >> 5, qd = (k >> 3) & 3, j = k & 7;
        const int idx = (((kt * 256 + c) << 2) + qd) * 8 + j;
        (which ? Wo : Wv)[idx] = (u16)f2bf(f);
    } else {                              // pack [W_off|W_attn] hi/lo (C=384)
        const int flat = (b - 512) * 256 + t;        // 0..98303
        const int k = flat / 384, c = flat - k * 384;
        const float f = (c < 256) ? W_off[k * 256 + c] : W_attn[k * 128 + (c - 256)];
        const short h = f2bf(f);
        const short lo = f2bf(f - bf2f(h));
        const int kt = k >> 5, qd = (k >> 3) & 3, j = k & 7;
        const int idx = (((kt * 384 + c) << 2) + qd) * 8 + j;
        Whi[idx] = (u16)h;
        Wlo[idx] = (u16)lo;
    }
}

// ---------------------------------------------------------------------------
// Kernel 1 (MFMA, read-once, software-pipelined): per-head bf16 layout
//   v_out[((n*M + m)*S_TOTAL + s)*32 + d] = mask * (value @ W_val + b_val)
// Each wave: 16 rows x full 256 cols. Double-buffered register pipeline:
// kt+1's A rows + 16 B-frags load while kt's 16 MFMAs issue.
// __launch_bounds__(256,2): ~256 VGPR budget so both buffers stay live
// (R7's 92-VGPR allocation serialized load->waitcnt->MFMA ~41k cyc/wave).
// ---------------------------------------------------------------------------
__global__ __launch_bounds__(256, 2) void vproj_kernel(
    const float* __restrict__ value,
    const float* __restrict__ vmask,
    const u16* __restrict__ Wpk,
    const float* __restrict__ b_val,
    u16* __restrict__ v_out)
{
    const int t  = threadIdx.x;
    const int w  = t >> 6, l = t & 63;
    const int c  = l & 15, qd = l >> 4;
    const int r0 = blockIdx.x * 64 + w * 16;

    const float* __restrict__ aptr = value + (size_t)(r0 + c) * EMBED + qd * 8;

    f32x4 acc[16] = {};

    s16x8 bcur[16], bnxt[16];
    float4 a0c, a1c, a0n, a1n;

    a0c = *(const float4*)(aptr);
    a1c = *(const float4*)(aptr + 4);
    #pragma unroll
    for (int nt = 0; nt < 16; ++nt)
        bcur[nt] = *(const s16x8*)(Wpk + (((nt * 16 + c) << 2) + qd) * 8);

    #pragma unroll
    for (int kt = 0; kt < 8; ++kt) {
        if (kt < 7) {
            a0n = *(const float4*)(aptr + (kt + 1) * 32);
            a1n = *(const float4*)(aptr + (kt + 1) * 32 + 4);
            #pragma unroll
            for (int nt = 0; nt < 16; ++nt)
                bnxt[nt] = *(const s16x8*)(Wpk + ((((kt + 1) * 256 + nt * 16 + c) << 2) + qd) * 8);
        }
        const s16x8 a = (s16x8){ f2bf(a0c.x), f2bf(a0c.y), f2bf(a0c.z), f2bf(a0c.w),
                                 f2bf(a1c.x), f2bf(a1c.y), f2bf(a1c.z), f2bf(a1c.w) };
        #pragma unroll
        for (int nt = 0; nt < 16; ++nt)
            acc[nt] = __builtin_amdgcn_mfma_f32_16x16x32_bf16(a, bcur[nt], acc[nt], 0, 0, 0);
        if (kt < 7) {
            a0c = a0n; a1c = a1n;
            #pragma unroll
            for (int nt = 0; nt < 16; ++nt) bcur[nt] = bnxt[nt];
        }
    }

    #pragma unroll
    for (int r = 0; r < 4; ++r) {
        const int grow = r0 + qd * 4 + r;
        const int n = (grow >= S_TOTAL) ? 1 : 0;
        const int s = grow - n * S_TOTAL;
        const float mk = vmask[grow];
        #pragma unroll
        for (int nt = 0; nt < 16; ++nt) {
            const int col = nt * 16 + c;
            const int hm = col >> 5, d = col & 31;
            v_out[((size_t)(n * M_HEADS + hm) * S_TOTAL + s) * DVAL + d] =
                (u16)f2bf((acc[nt][r] + b_val[col]) * mk);
        }
    }
}

// ---------------------------------------------------------------------------
// Kernel 2 (split-bf16 MFMA): [offsets | attn] = q @ [W_off|W_attn] + bias
// via 3-pass hi/lo MFMA. Queries read as fp32 and split to hi/lo frags
// in-register (presplit kernel removed). 32 rows/block, 4 waves x 96 cols.
// ---------------------------------------------------------------------------
__global__ __launch_bounds__(256) void qproj_kernel(
    const float* __restrict__ queries,
    const float* __restrict__ qgl,
    const u16* __restrict__ Whi, const u16* __restrict__ Wlo,
    const float* __restrict__ b_off, const float* __restrict__ b_attn,
    float* __restrict__ pa)
{
    __shared__ float s_off[32][260];
    __shared__ float s_attn[32][132];
    __shared__ float s_geom[32][4];

    const int t  = threadIdx.x;
    const int w  = t >> 6, l = t & 63;
    const int c  = l & 15, qd = l >> 4;
    const int row0 = blockIdx.x * 32;
    const int c0 = w * 96;

    if (t < 32) {
        const float* g = &qgl[(size_t)(row0 + t) * 4];
        s_geom[t][0] = 1.f / (1.f + __expf(-g[0]));
        s_geom[t][1] = 1.f / (1.f + __expf(-g[1]));
        s_geom[t][2] = (1.f / (1.f + __expf(-g[2]))) * 0.125f;
        s_geom[t][3] = (1.f / (1.f + __expf(-g[3]))) * 0.125f;
    }

    f32x4 acc[2][6] = {};

    for (int kt = 0; kt < 8; ++kt) {
        s16x8 ah[2], al[2], bh[6], bl[6];
        #pragma unroll
        for (int mt = 0; mt < 2; ++mt) {
            const float* qp = queries + (size_t)(row0 + mt * 16 + c) * EMBED + kt * 32 + qd * 8;
            const float4 v0 = *(const float4*)qp;
            const float4 v1 = *(const float4*)(qp + 4);
            const short h0 = f2bf(v0.x), h1 = f2bf(v0.y), h2 = f2bf(v0.z), h3 = f2bf(v0.w);
            const short h4 = f2bf(v1.x), h5 = f2bf(v1.y), h6 = f2bf(v1.z), h7 = f2bf(v1.w);
            ah[mt] = (s16x8){ h0, h1, h2, h3, h4, h5, h6, h7 };
            al[mt] = (s16x8){ f2bf(v0.x - bf2f(h0)), f2bf(v0.y - bf2f(h1)),
                              f2bf(v0.z - bf2f(h2)), f2bf(v0.w - bf2f(h3)),
                              f2bf(v1.x - bf2f(h4)), f2bf(v1.y - bf2f(h5)),
                              f2bf(v1.z - bf2f(h6)), f2bf(v1.w - bf2f(h7)) };
        }
        #pragma unroll
        for (int nt = 0; nt < 6; ++nt) {
            const int idx = (((kt * 384 + c0 + nt * 16 + c) << 2) + qd) * 8;
            bh[nt] = *(const s16x8*)(Whi + idx);
            bl[nt] = *(const s16x8*)(Wlo + idx);
        }
        #pragma unroll
        for (int mt = 0; mt < 2; ++mt)
            #pragma unroll
            for (int nt = 0; nt < 6; ++nt) {
                acc[mt][nt] = __builtin_amdgcn_mfma_f32_16x16x32_bf16(ah[mt], bh[nt], acc[mt][nt], 0, 0, 0);
                acc[mt][nt] = __builtin_amdgcn_mfma_f32_16x16x32_bf16(ah[mt], bl[nt], acc[mt][nt], 0, 0, 0);
                acc[mt][nt] = __builtin_amdgcn_mfma_f32_16x16x32_bf16(al[mt], bh[nt], acc[mt][nt], 0, 0, 0);
            }
    }

    #pragma unroll
    for (int mt = 0; mt < 2; ++mt)
        #pragma unroll
        for (int nt = 0; nt < 6; ++nt) {
            const int col = c0 + nt * 16 + c;
            #pragma unroll
            for (int r = 0; r < 4; ++r) {
                const int row = mt * 16 + qd * 4 + r;
                if (col < 256) s_off[row][col] = acc[mt][nt][r] + b_off[col];
                else           s_attn[row][col - 256] = acc[mt][nt][r] + b_attn[col - 256];
            }
        }
    __syncthreads();

    {
        const int qi = t >> 3, hm = t & 7;
        float* a = &s_attn[qi][hm * LK];
        float mx = a[0];
        #pragma unroll
        for (int i = 1; i < LK; ++i) mx = fmaxf(mx, a[i]);
        float s = 0.f;
        #pragma unroll
        for (int i = 0; i < LK; ++i) { const float e = __expf(a[i] - mx); a[i] = e; s += e; }
        const float inv = 1.f / s;
        #pragma unroll
        for (int i = 0; i < LK; ++i) a[i] *= inv;
    }
    __syncthreads();

    for (int p = t; p < 32 * 128; p += 256) {
        const int qi = p >> 7;
        const int pt = p & 127;
        const int lvl = (pt & 15) >> 2;
        const float Wl = (float)(128 >> lvl);
        const float px = fmaf(s_off[qi][2 * pt + 0], s_geom[qi][2], s_geom[qi][0]);
        const float py = fmaf(s_off[qi][2 * pt + 1], s_geom[qi][3], s_geom[qi][1]);
        const float gx = fminf(fmaxf(2.f * px - 1.f, -1.f), 1.f);
        const float gy = fminf(fmaxf(2.f * py - 1.f, -1.f), 1.f);
        const float x = (gx + 1.f) * (Wl * 0.5f) - 0.5f;
        const float y = (gy + 1.f) * (Wl * 0.5f) - 0.5f;
        const size_t idx = ((size_t)(row0 + qi) * 128 + pt) * 3;
        pa[idx + 0] = x;
        pa[idx + 1] = y;
        pa[idx + 2] = s_attn[qi][pt];
    }
}

// ---------------------------------------------------------------------------
// Kernel 3: bilinear sampling. Setup: 256 pts/block -> LDS int4 offsets +
// float4 weights. Main: 2 bf16 channels per lane via dword gathers.
// m = blk&7 keeps one head's slice L2-local per XCD.
// ---------------------------------------------------------------------------
__global__ __launch_bounds__(256) void sample_kernel(
    const float* __restrict__ pa,
    const u16* __restrict__ v_tab,
    u16* __restrict__ mid)
{
    __shared__ int4   s_idx[QBS * 17];
    __shared__ float4 s_w[QBS * 17];

    const int t    = threadIdx.x;
    const int m    = blockIdx.x & 7;
    const int rest = blockIdx.x >> 3;
    const int qc   = rest & 511;
    const int n    = rest >> 9;
    const int q0   = qc * QBS;

    {
        const int qi = t >> 4, lk = t & 15;
        const int lvl   = lk >> 2;
        const int Wl    = 128 >> lvl;
        const int start = (lvl == 0) ? 0 : (lvl == 1) ? 16384 : (lvl == 2) ? 20480 : 21504;

        const size_t prow = ((size_t)(n * NQ + q0 + qi)) * 128 + m * 16 + lk;
        const float x  = pa[prow * 3 + 0];
        const float y  = pa[prow * 3 + 1];
        const float aw = pa[prow * 3 + 2];

        const float x0f = floorf(x), y0f = floorf(y);
        const int   x0 = (int)x0f, y0 = (int)y0f;
        const float wx = x - x0f, wy = y - y0f;

        const float vx0 = (x0 >= 0) ? 1.f : 0.f;
        const float vx1 = (x0 + 1 <= Wl - 1) ? 1.f : 0.f;
        const float vy0 = (y0 >= 0) ? 1.f : 0.f;
        const float vy1 = (y0 + 1 <= Wl - 1) ? 1.f : 0.f;

        const int xc0 = max(x0, 0);
        const int xc1 = min(x0 + 1, Wl - 1);
        const int yc0 = max(y0, 0);
        const int yc1 = min(y0 + 1, Wl - 1);

        const int e = qi * 17 + lk;
        s_idx[e] = make_int4((start + yc0 * Wl + xc0) * DVAL,
                             (start + yc0 * Wl + xc1) * DVAL,
                             (start + yc1 * Wl + xc0) * DVAL,
                             (start + yc1 * Wl + xc1) * DVAL);
        s_w[e] = make_float4(aw * (1.f - wx) * (1.f - wy) * vx0 * vy0,
                             aw * wx * (1.f - wy) * vx1 * vy0,
                             aw * (1.f - wx) * wy * vx0 * vy1,
                             aw * wx * wy * vx1 * vy1);
    }
    __syncthreads();

    const int g = t >> 4, dp = t & 15;
    const u16* __restrict__ vbp =
        v_tab + (size_t)(n * M_HEADS + m) * S_TOTAL * DVAL + 2 * dp;

    float acc0 = 0.f, acc1 = 0.f;
    #pragma unroll
    for (int lk = 0; lk < LK; ++lk) {
        const int4   id = s_idx[g * 17 + lk];
        const float4 w  = s_w[g * 17 + lk];
        const u32 u0 = *(const u32*)(vbp + id.x);
        const u32 u1 = *(const u32*)(vbp + id.y);
        const u32 u2 = *(const u32*)(vbp + id.z);
        const u32 u3 = *(const u32*)(vbp + id.w);
        acc0 = fmaf(w.x, __uint_as_float(u0 << 16), acc0);
        acc1 = fmaf(w.x, __uint_as_float(u0 & 0xffff0000u), acc1);
        acc0 = fmaf(w.y, __uint_as_float(u1 << 16), acc0);
        acc1 = fmaf(w.y, __uint_as_float(u1 & 0xffff0000u), acc1);
        acc0 = fmaf(w.z, __uint_as_float(u2 << 16), acc0);
        acc1 = fmaf(w.z, __uint_as_float(u2 & 0xffff0000u), acc1);
        acc0 = fmaf(w.w, __uint_as_float(u3 << 16), acc0);
        acc1 = fmaf(w.w, __uint_as_float(u3 & 0xffff0000u), acc1);
    }

    const u32 packed = ((u32)(u16)f2bf(acc1) << 16) | (u32)(u16)f2bf(acc0);
    *(u32*)(mid + ((size_t)(n * NQ + q0 + g)) * EMBED + m * DVAL + 2 * dp) = packed;
}

// ---------------------------------------------------------------------------
// Kernel 4 (MFMA, LDS-free): out = mid @ W_out + b_out.
// ---------------------------------------------------------------------------
__global__ __launch_bounds__(256) void out_kernel(
    const u16* __restrict__ mid,
    const u16* __restrict__ Wpk,
    const float* __restrict__ b_out,
    float* __restrict__ out)
{
    const int t  = threadIdx.x;
    const int w  = t >> 6, l = t & 63;
    const int c  = l & 15, qd = l >> 4;
    const int r0 = blockIdx.y * 128 + w * 32;
    const int c0 = blockIdx.x * 64;

    f32x4 acc[2][4] = {};

    for (int kt = 0; kt < 8; ++kt) {
        s16x8 a[2], b[4];
        #pragma unroll
        for (int mt = 0; mt < 2; ++mt)
            a[mt] = *(const s16x8*)(mid + (size_t)(r0 + mt * 16 + c) * EMBED + kt * 32 + qd * 8);
        #pragma unroll
        for (int nt = 0; nt < 4; ++nt)
            b[nt] = *(const s16x8*)(Wpk + (((kt * 256 + c0 + nt * 16 + c) << 2) + qd) * 8);
        #pragma unroll
        for (int mt = 0; mt < 2; ++mt)
            #pragma unroll
            for (int nt = 0; nt < 4; ++nt)
                acc[mt][nt] = __builtin_amdgcn_mfma_f32_16x16x32_bf16(a[mt], b[nt], acc[mt][nt], 0, 0, 0);
    }

    #pragma unroll
    for (int mt = 0; mt < 2; ++mt)
        #pragma unroll
        for (int r = 0; r < 4; ++r) {
            const int row = r0 + mt * 16 + qd * 4 + r;
            #pragma unroll
            for (int nt = 0; nt < 4; ++nt) {
                const int col = c0 + nt * 16 + c;
                out[(size_t)row * EMBED + col] = acc[mt][nt][r] + b_out[col];
            }
        }
}

// ---------------------------------------------------------------------------
extern "C" void kernel_launch(void* const* d_in, const int* in_sizes, int n_in,
                              void* d_out, int out_size, void* d_ws, size_t ws_size,
                              hipStream_t stream) {
    (void)in_sizes; (void)n_in; (void)out_size; (void)ws_size;

    const float* queries = (const float*)d_in[0];
    const float* qgl     = (const float*)d_in[1];
    const float* value   = (const float*)d_in[2];
    const float* vmask   = (const float*)d_in[3];
    const float* W_off   = (const float*)d_in[4];
    const float* b_off   = (const float*)d_in[5];
    const float* W_attn  = (const float*)d_in[6];
    const float* b_attn  = (const float*)d_in[7];
    const float* W_val   = (const float*)d_in[8];
    const float* b_val   = (const float*)d_in[9];
    const float* W_out   = (const float*)d_in[10];
    const float* b_out   = (const float*)d_in[11];

    float* ws   = (float*)d_ws;
    u16*  v_ws  = (u16*)(ws + V_OFF);
    float* pa   = ws + PA_OFF;
    u16*  mid   = (u16*)(ws + MID_OFF);
    u16*  whi   = (u16*)(ws + WHI_OFF);
    u16*  wlo   = (u16*)(ws + WLO_OFF);
    u16*  wvpk  = (u16*)(ws + WV_OFF);
    u16*  wopk  = (u16*)(ws + WO_OFF);
    float* outp = (float*)d_out;

    prep_kernel<<<896, 256, 0, stream>>>(W_off, W_attn, whi, wlo,
                                         W_val, wvpk, W_out, wopk);

    vproj_kernel<<<680, 256, 0, stream>>>(value, vmask, wvpk, b_val, v_ws);
    qproj_kernel<<<NROWS / 32, 256, 0, stream>>>(queries, qgl, whi, wlo,
                                                 b_off, b_attn, pa);
    sample_kernel<<<2 * (NQ / QBS) * M_HEADS, 256, 0, stream>>>(pa, v_ws, mid);
    out_kernel<<<dim3(4, 128), 256, 0, stream>>>(mid, wopk, b_out, outp);
}

// Round 9
// 205.087 us; speedup vs baseline: 1.0882x; 1.0419x over previous
//
#include <hip/hip_runtime.h>
#include <math.h>

#define EMBED   256
#define M_HEADS 8
#define DVAL    32
#define LK      16
#define S_TOTAL 21760
#define NQ      8192
#define NROWS   (2 * NQ)          // 16384 total query rows
#define QBS     16                // queries per block (sample)

typedef __attribute__((ext_vector_type(8))) short s16x8;
typedef __attribute__((ext_vector_type(4))) float f32x4;
typedef unsigned short u16;
typedef unsigned int   u32;

__device__ __forceinline__ short f2bf(float f) {
    unsigned u = __float_as_uint(f);
    u += 0x7fffu + ((u >> 16) & 1u);
    return (short)(u >> 16);
}
__device__ __forceinline__ float bf2f(short h) {
    return __uint_as_float(((unsigned)(u16)h) << 16);
}

// ---------------- workspace layout (float offsets) ----------------
#define V_OFF     0                      // value table, bf16: 11,141,120 shorts
#define V_FLTS    5570560
#define PA_OFF    (V_OFF + V_FLTS)       // (x,y,attn) fp32 triples
#define PA_FLTS   6291456
#define MID_OFF   (PA_OFF + PA_FLTS)     // mid bf16 [16384][256]
#define MID_FLTS  2097152
#define WHI_OFF   (MID_OFF + MID_FLTS)   // packed [W_off|W_attn] hi, C=384
#define WOA_FLTS  49152
#define WLO_OFF   (WHI_OFF + WOA_FLTS)
#define WV_OFF    (WLO_OFF + WOA_FLTS)   // packed W_val bf16, C=256
#define WO_OFF    (WV_OFF + 32768)       // packed W_out bf16, C=256

// ---------------------------------------------------------------------------
// prep_kernel (weight packs only): blocks 0..511 pack W_val/W_out (C=256),
// blocks 512..895 pack [W_off|W_attn] hi/lo (C=384).
// ---------------------------------------------------------------------------
__global__ __launch_bounds__(256) void prep_kernel(
    const float* __restrict__ W_off, const float* __restrict__ W_attn,
    u16* __restrict__ Whi,           u16* __restrict__ Wlo,
    const float* __restrict__ W_val, u16* __restrict__ Wv,
    const float* __restrict__ W_out, u16* __restrict__ Wo)
{
    const int b = blockIdx.x;
    const int t = threadIdx.x;

    if (b < 512) {                        // pack W_val / W_out (C=256)
        const int flat = b * 256 + t;                // 0..131071
        const int which = flat >> 16;                // 0: W_val, 1: W_out
        const int e = flat & 65535;
        const int k = e >> 8, c = e & 255;
        const float f = which ? W_out[k * 256 + c] : W_val[k * 256 + c];
        const int kt = k >> 5, qd = (k >> 3) & 3, j = k & 7;
        const int idx = (((kt * 256 + c) << 2) + qd) * 8 + j;
        (which ? Wo : Wv)[idx] = (u16)f2bf(f);
    } else {                              // pack [W_off|W_attn] hi/lo (C=384)
        const int flat = (b - 512) * 256 + t;        // 0..98303
        const int k = flat / 384, c = flat - k * 384;
        const float f = (c < 256) ? W_off[k * 256 + c] : W_attn[k * 128 + (c - 256)];
        const short h = f2bf(f);
        const short lo = f2bf(f - bf2f(h));
        const int kt = k >> 5, qd = (k >> 3) & 3, j = k & 7;
        const int idx = (((kt * 384 + c) << 2) + qd) * 8 + j;
        Whi[idx] = (u16)h;
        Wlo[idx] = (u16)lo;
    }
}

// ---------------------------------------------------------------------------
// Kernel 1 (MFMA, B-resident): v = mask * (value @ W_val + b_val), per-head
// bf16 layout v_out[((n*M + m)*S_TOTAL + s)*32 + d].
// Wave w owns cols [w*64, w*64+64): ALL 32 B-frags (8kt x 4nt, 128 VGPR)
// preloaded ONCE; grid-stride over 16-row A-tiles (2720 tiles, grid 512).
// Per tile: 16 independent A-loads -> 32 MFMAs; no per-kt B reload.
// ---------------------------------------------------------------------------
__global__ __launch_bounds__(256, 2) void vproj_kernel(
    const float* __restrict__ value,
    const float* __restrict__ vmask,
    const u16* __restrict__ Wpk,
    const float* __restrict__ b_val,
    u16* __restrict__ v_out)
{
    const int t  = threadIdx.x;
    const int w  = t >> 6, l = t & 63;
    const int c  = l & 15, qd = l >> 4;
    const int c0 = w * 64;

    s16x8 B[8][4];
    #pragma unroll
    for (int kt = 0; kt < 8; ++kt)
        #pragma unroll
        for (int nt = 0; nt < 4; ++nt)
            B[kt][nt] = *(const s16x8*)(Wpk + (((kt * 256 + c0 + nt * 16 + c) << 2) + qd) * 8);

    float bias[4];
    #pragma unroll
    for (int nt = 0; nt < 4; ++nt) bias[nt] = b_val[c0 + nt * 16 + c];

    for (int tile = blockIdx.x; tile < 2720; tile += 512) {
        const int r0 = tile * 16;
        const float* __restrict__ ap = value + (size_t)(r0 + c) * EMBED + qd * 8;

        // burst-load all 8 kt A rows (16 independent 16B loads)
        float4 a0[8], a1[8];
        #pragma unroll
        for (int kt = 0; kt < 8; ++kt) {
            a0[kt] = *(const float4*)(ap + kt * 32);
            a1[kt] = *(const float4*)(ap + kt * 32 + 4);
        }

        f32x4 acc[4] = {};
        #pragma unroll
        for (int kt = 0; kt < 8; ++kt) {
            const s16x8 a = (s16x8){ f2bf(a0[kt].x), f2bf(a0[kt].y), f2bf(a0[kt].z), f2bf(a0[kt].w),
                                     f2bf(a1[kt].x), f2bf(a1[kt].y), f2bf(a1[kt].z), f2bf(a1[kt].w) };
            #pragma unroll
            for (int nt = 0; nt < 4; ++nt)
                acc[nt] = __builtin_amdgcn_mfma_f32_16x16x32_bf16(a, B[kt][nt], acc[nt], 0, 0, 0);
        }

        #pragma unroll
        for (int r = 0; r < 4; ++r) {
            const int grow = r0 + qd * 4 + r;
            const int n = (grow >= S_TOTAL) ? 1 : 0;
            const int s = grow - n * S_TOTAL;
            const float mk = vmask[grow];
            #pragma unroll
            for (int nt = 0; nt < 4; ++nt) {
                const int col = c0 + nt * 16 + c;
                const int hm = col >> 5, d = col & 31;
                v_out[((size_t)(n * M_HEADS + hm) * S_TOTAL + s) * DVAL + d] =
                    (u16)f2bf((acc[nt][r] + bias[nt]) * mk);
            }
        }
    }
}

// ---------------------------------------------------------------------------
// Kernel 2 (split-bf16 MFMA): [offsets | attn] = q @ [W_off|W_attn] + bias
// via 3-pass hi/lo MFMA. Queries read as fp32 and split to hi/lo frags
// in-register. 32 rows/block, 4 waves x 96 cols.
// ---------------------------------------------------------------------------
__global__ __launch_bounds__(256) void qproj_kernel(
    const float* __restrict__ queries,
    const float* __restrict__ qgl,
    const u16* __restrict__ Whi, const u16* __restrict__ Wlo,
    const float* __restrict__ b_off, const float* __restrict__ b_attn,
    float* __restrict__ pa)
{
    __shared__ float s_off[32][260];
    __shared__ float s_attn[32][132];
    __shared__ float s_geom[32][4];

    const int t  = threadIdx.x;
    const int w  = t >> 6, l = t & 63;
    const int c  = l & 15, qd = l >> 4;
    const int row0 = blockIdx.x * 32;
    const int c0 = w * 96;

    if (t < 32) {
        const float* g = &qgl[(size_t)(row0 + t) * 4];
        s_geom[t][0] = 1.f / (1.f + __expf(-g[0]));
        s_geom[t][1] = 1.f / (1.f + __expf(-g[1]));
        s_geom[t][2] = (1.f / (1.f + __expf(-g[2]))) * 0.125f;
        s_geom[t][3] = (1.f / (1.f + __expf(-g[3]))) * 0.125f;
    }

    f32x4 acc[2][6] = {};

    for (int kt = 0; kt < 8; ++kt) {
        s16x8 ah[2], al[2], bh[6], bl[6];
        #pragma unroll
        for (int mt = 0; mt < 2; ++mt) {
            const float* qp = queries + (size_t)(row0 + mt * 16 + c) * EMBED + kt * 32 + qd * 8;
            const float4 v0 = *(const float4*)qp;
            const float4 v1 = *(const float4*)(qp + 4);
            const short h0 = f2bf(v0.x), h1 = f2bf(v0.y), h2 = f2bf(v0.z), h3 = f2bf(v0.w);
            const short h4 = f2bf(v1.x), h5 = f2bf(v1.y), h6 = f2bf(v1.z), h7 = f2bf(v1.w);
            ah[mt] = (s16x8){ h0, h1, h2, h3, h4, h5, h6, h7 };
            al[mt] = (s16x8){ f2bf(v0.x - bf2f(h0)), f2bf(v0.y - bf2f(h1)),
                              f2bf(v0.z - bf2f(h2)), f2bf(v0.w - bf2f(h3)),
                              f2bf(v1.x - bf2f(h4)), f2bf(v1.y - bf2f(h5)),
                              f2bf(v1.z - bf2f(h6)), f2bf(v1.w - bf2f(h7)) };
        }
        #pragma unroll
        for (int nt = 0; nt < 6; ++nt) {
            const int idx = (((kt * 384 + c0 + nt * 16 + c) << 2) + qd) * 8;
            bh[nt] = *(const s16x8*)(Whi + idx);
            bl[nt] = *(const s16x8*)(Wlo + idx);
        }
        #pragma unroll
        for (int mt = 0; mt < 2; ++mt)
            #pragma unroll
            for (int nt = 0; nt < 6; ++nt) {
                acc[mt][nt] = __builtin_amdgcn_mfma_f32_16x16x32_bf16(ah[mt], bh[nt], acc[mt][nt], 0, 0, 0);
                acc[mt][nt] = __builtin_amdgcn_mfma_f32_16x16x32_bf16(ah[mt], bl[nt], acc[mt][nt], 0, 0, 0);
                acc[mt][nt] = __builtin_amdgcn_mfma_f32_16x16x32_bf16(al[mt], bh[nt], acc[mt][nt], 0, 0, 0);
            }
    }

    #pragma unroll
    for (int mt = 0; mt < 2; ++mt)
        #pragma unroll
        for (int nt = 0; nt < 6; ++nt) {
            const int col = c0 + nt * 16 + c;
            #pragma unroll
            for (int r = 0; r < 4; ++r) {
                const int row = mt * 16 + qd * 4 + r;
                if (col < 256) s_off[row][col] = acc[mt][nt][r] + b_off[col];
                else           s_attn[row][col - 256] = acc[mt][nt][r] + b_attn[col - 256];
            }
        }
    __syncthreads();

    {
        const int qi = t >> 3, hm = t & 7;
        float* a = &s_attn[qi][hm * LK];
        float mx = a[0];
        #pragma unroll
        for (int i = 1; i < LK; ++i) mx = fmaxf(mx, a[i]);
        float s = 0.f;
        #pragma unroll
        for (int i = 0; i < LK; ++i) { const float e = __expf(a[i] - mx); a[i] = e; s += e; }
        const float inv = 1.f / s;
        #pragma unroll
        for (int i = 0; i < LK; ++i) a[i] *= inv;
    }
    __syncthreads();

    for (int p = t; p < 32 * 128; p += 256) {
        const int qi = p >> 7;
        const int pt = p & 127;
        const int lvl = (pt & 15) >> 2;
        const float Wl = (float)(128 >> lvl);
        const float px = fmaf(s_off[qi][2 * pt + 0], s_geom[qi][2], s_geom[qi][0]);
        const float py = fmaf(s_off[qi][2 * pt + 1], s_geom[qi][3], s_geom[qi][1]);
        const float gx = fminf(fmaxf(2.f * px - 1.f, -1.f), 1.f);
        const float gy = fminf(fmaxf(2.f * py - 1.f, -1.f), 1.f);
        const float x = (gx + 1.f) * (Wl * 0.5f) - 0.5f;
        const float y = (gy + 1.f) * (Wl * 0.5f) - 0.5f;
        const size_t idx = ((size_t)(row0 + qi) * 128 + pt) * 3;
        pa[idx + 0] = x;
        pa[idx + 1] = y;
        pa[idx + 2] = s_attn[qi][pt];
    }
}

// ---------------------------------------------------------------------------
// Kernel 3: bilinear sampling. Setup: 256 pts/block -> LDS int4 offsets +
// float4 weights. Main: 2 bf16 channels per lane via dword gathers.
// m = blk&7 keeps one head's slice L2-local per XCD.
// ---------------------------------------------------------------------------
__global__ __launch_bounds__(256) void sample_kernel(
    const float* __restrict__ pa,
    const u16* __restrict__ v_tab,
    u16* __restrict__ mid)
{
    __shared__ int4   s_idx[QBS * 17];
    __shared__ float4 s_w[QBS * 17];

    const int t    = threadIdx.x;
    const int m    = blockIdx.x & 7;
    const int rest = blockIdx.x >> 3;
    const int qc   = rest & 511;
    const int n    = rest >> 9;
    const int q0   = qc * QBS;

    {
        const int qi = t >> 4, lk = t & 15;
        const int lvl   = lk >> 2;
        const int Wl    = 128 >> lvl;
        const int start = (lvl == 0) ? 0 : (lvl == 1) ? 16384 : (lvl == 2) ? 20480 : 21504;

        const size_t prow = ((size_t)(n * NQ + q0 + qi)) * 128 + m * 16 + lk;
        const float x  = pa[prow * 3 + 0];
        const float y  = pa[prow * 3 + 1];
        const float aw = pa[prow * 3 + 2];

        const float x0f = floorf(x), y0f = floorf(y);
        const int   x0 = (int)x0f, y0 = (int)y0f;
        const float wx = x - x0f, wy = y - y0f;

        const float vx0 = (x0 >= 0) ? 1.f : 0.f;
        const float vx1 = (x0 + 1 <= Wl - 1) ? 1.f : 0.f;
        const float vy0 = (y0 >= 0) ? 1.f : 0.f;
        const float vy1 = (y0 + 1 <= Wl - 1) ? 1.f : 0.f;

        const int xc0 = max(x0, 0);
        const int xc1 = min(x0 + 1, Wl - 1);
        const int yc0 = max(y0, 0);
        const int yc1 = min(y0 + 1, Wl - 1);

        const int e = qi * 17 + lk;
        s_idx[e] = make_int4((start + yc0 * Wl + xc0) * DVAL,
                             (start + yc0 * Wl + xc1) * DVAL,
                             (start + yc1 * Wl + xc0) * DVAL,
                             (start + yc1 * Wl + xc1) * DVAL);
        s_w[e] = make_float4(aw * (1.f - wx) * (1.f - wy) * vx0 * vy0,
                             aw * wx * (1.f - wy) * vx1 * vy0,
                             aw * (1.f - wx) * wy * vx0 * vy1,
                             aw * wx * wy * vx1 * vy1);
    }
    __syncthreads();

    const int g = t >> 4, dp = t & 15;
    const u16* __restrict__ vbp =
        v_tab + (size_t)(n * M_HEADS + m) * S_TOTAL * DVAL + 2 * dp;

    float acc0 = 0.f, acc1 = 0.f;
    #pragma unroll
    for (int lk = 0; lk < LK; ++lk) {
        const int4   id = s_idx[g * 17 + lk];
        const float4 w  = s_w[g * 17 + lk];
        const u32 u0 = *(const u32*)(vbp + id.x);
        const u32 u1 = *(const u32*)(vbp + id.y);
        const u32 u2 = *(const u32*)(vbp + id.z);
        const u32 u3 = *(const u32*)(vbp + id.w);
        acc0 = fmaf(w.x, __uint_as_float(u0 << 16), acc0);
        acc1 = fmaf(w.x, __uint_as_float(u0 & 0xffff0000u), acc1);
        acc0 = fmaf(w.y, __uint_as_float(u1 << 16), acc0);
        acc1 = fmaf(w.y, __uint_as_float(u1 & 0xffff0000u), acc1);
        acc0 = fmaf(w.z, __uint_as_float(u2 << 16), acc0);
        acc1 = fmaf(w.z, __uint_as_float(u2 & 0xffff0000u), acc1);
        acc0 = fmaf(w.w, __uint_as_float(u3 << 16), acc0);
        acc1 = fmaf(w.w, __uint_as_float(u3 & 0xffff0000u), acc1);
    }

    const u32 packed = ((u32)(u16)f2bf(acc1) << 16) | (u32)(u16)f2bf(acc0);
    *(u32*)(mid + ((size_t)(n * NQ + q0 + g)) * EMBED + m * DVAL + 2 * dp) = packed;
}

// ---------------------------------------------------------------------------
// Kernel 4 (MFMA, B-resident): out = mid @ W_out + b_out. Same structure as
// vproj: wave owns 64 cols, 32 B-frags preloaded once, grid-stride over
// 16-row A-tiles (1024 tiles, grid 512 x 2).
// ---------------------------------------------------------------------------
__global__ __launch_bounds__(256, 2) void out_kernel(
    const u16* __restrict__ mid,
    const u16* __restrict__ Wpk,
    const float* __restrict__ b_out,
    float* __restrict__ out)
{
    const int t  = threadIdx.x;
    const int w  = t >> 6, l = t & 63;
    const int c  = l & 15, qd = l >> 4;
    const int c0 = w * 64;

    s16x8 B[8][4];
    #pragma unroll
    for (int kt = 0; kt < 8; ++kt)
        #pragma unroll
        for (int nt = 0; nt < 4; ++nt)
            B[kt][nt] = *(const s16x8*)(Wpk + (((kt * 256 + c0 + nt * 16 + c) << 2) + qd) * 8);

    float bias[4];
    #pragma unroll
    for (int nt = 0; nt < 4; ++nt) bias[nt] = b_out[c0 + nt * 16 + c];

    for (int tile = blockIdx.x; tile < 1024; tile += 512) {
        const int r0 = tile * 16;
        const u16* __restrict__ ap = mid + (size_t)(r0 + c) * EMBED + qd * 8;

        s16x8 a[8];
        #pragma unroll
        for (int kt = 0; kt < 8; ++kt)
            a[kt] = *(const s16x8*)(ap + kt * 32);

        f32x4 acc[4] = {};
        #pragma unroll
        for (int kt = 0; kt < 8; ++kt)
            #pragma unroll
            for (int nt = 0; nt < 4; ++nt)
                acc[nt] = __builtin_amdgcn_mfma_f32_16x16x32_bf16(a[kt], B[kt][nt], acc[nt], 0, 0, 0);

        #pragma unroll
        for (int r = 0; r < 4; ++r) {
            const int row = r0 + qd * 4 + r;
            #pragma unroll
            for (int nt = 0; nt < 4; ++nt)
                out[(size_t)row * EMBED + c0 + nt * 16 + c] = acc[nt][r] + bias[nt];
        }
    }
}

// ---------------------------------------------------------------------------
extern "C" void kernel_launch(void* const* d_in, const int* in_sizes, int n_in,
                              void* d_out, int out_size, void* d_ws, size_t ws_size,
                              hipStream_t stream) {
    (void)in_sizes; (void)n_in; (void)out_size; (void)ws_size;

    const float* queries = (const float*)d_in[0];
    const float* qgl     = (const float*)d_in[1];
    const float* value   = (const float*)d_in[2];
    const float* vmask   = (const float*)d_in[3];
    const float* W_off   = (const float*)d_in[4];
    const float* b_off   = (const float*)d_in[5];
    const float* W_attn  = (const float*)d_in[6];
    const float* b_attn  = (const float*)d_in[7];
    const float* W_val   = (const float*)d_in[8];
    const float* b_val   = (const float*)d_in[9];
    const float* W_out   = (const float*)d_in[10];
    const float* b_out   = (const float*)d_in[11];

    float* ws   = (float*)d_ws;
    u16*  v_ws  = (u16*)(ws + V_OFF);
    float* pa   = ws + PA_OFF;
    u16*  mid   = (u16*)(ws + MID_OFF);
    u16*  whi   = (u16*)(ws + WHI_OFF);
    u16*  wlo   = (u16*)(ws + WLO_OFF);
    u16*  wvpk  = (u16*)(ws + WV_OFF);
    u16*  wopk  = (u16*)(ws + WO_OFF);
    float* outp = (float*)d_out;

    prep_kernel<<<896, 256, 0, stream>>>(W_off, W_attn, whi, wlo,
                                         W_val, wvpk, W_out, wopk);

    vproj_kernel<<<512, 256, 0, stream>>>(value, vmask, wvpk, b_val, v_ws);
    qproj_kernel<<<NROWS / 32, 256, 0, stream>>>(queries, qgl, whi, wlo,
                                                 b_off, b_attn, pa);
    sample_kernel<<<2 * (NQ / QBS) * M_HEADS, 256, 0, stream>>>(pa, v_ws, mid);
    out_kernel<<<512, 256, 0, stream>>>(mid, wopk, b_out, outp);
}